// Round 8
// baseline (207.066 us; speedup 1.0000x reference)
//
#include <hip/hip_runtime.h>
#include <math.h>

#define B_   2
#define N_   2048
#define D_   1024
#define H_   16
#define HD_  64
#define BH_  32
#define M_   4096   // B_*N_

typedef __bf16 bf16x8 __attribute__((ext_vector_type(8)));
typedef float  f32x4  __attribute__((ext_vector_type(4)));

__device__ inline unsigned short f2b(float f) {
    unsigned u = __float_as_uint(f);
    u += 0x7FFFu + ((u >> 16) & 1u);
    return (unsigned short)(u >> 16);
}
// cheap round (1 ulp vs RNE on ties; P has huge margin)
__device__ inline unsigned short f2b_fast(float f) {
    return (unsigned short)((__float_as_uint(f) + 0x8000u) >> 16);
}

// ---------------------------------------------------------------------------
// Convert x (4096x1024) and Wq/Wk/Wv/Wo (1024x1024 each) fp32 -> bf16 into one
// contiguous ws region: [x | wq | wk | wv | wo].
// ---------------------------------------------------------------------------
__global__ __launch_bounds__(256)
void cvt_all(const float* __restrict__ x,  const float* __restrict__ wq,
             const float* __restrict__ wk, const float* __restrict__ wv,
             const float* __restrict__ wo, ushort* __restrict__ dst)
{
    int i = blockIdx.x * 256 + threadIdx.x;      // float4 index
    if (i >= 2097152) return;                    // (4096*1024 + 4*1024*1024)/4
    int fi = i * 4;
    const float* s; int off;
    if (fi < 4194304) { s = x; off = fi; }
    else {
        int r = fi - 4194304;
        int wsel = r >> 20;                      // each W = 2^20 elements
        off = r & 1048575;
        s = (wsel == 0) ? wq : (wsel == 1) ? wk : (wsel == 2) ? wv : wo;
    }
    float4 f = *(const float4*)(s + off);
    ushort4 o;
    o.x = f2b(f.x); o.y = f2b(f.y); o.z = f2b(f.z); o.w = f2b(f.w);
    *(ushort4*)(dst + fi) = o;
}

// ---------------------------------------------------------------------------
// QKV bf16 MFMA GEMM: C = A @ W^T. A [Mx1024], W [1024x1024], both row-major.
// 128x128 tile, 4 waves 2x2, 64x64/wave, BK=32. Register-prefetch staging
// (R6/R7 pattern). LDS padded [128][40].
// z=0 (Q): scaled by 0.125*log2e (scores in log2 domain for exp2-native
//          softmax) -> [BH][N][64]
// z=1 (K): [BH][N][64];  z=2 (V): TRANSPOSED [BH][HD][N] (ushort4 stores).
// Layouts (HW-verified m89/m91/m120): A-frag (m=lane&15, k=quad*8+j),
// B-frag (k=quad*8+j, n=lane&15), C/D col=lane&15, row=quad*4+reg.
// ---------------------------------------------------------------------------
__global__ __launch_bounds__(256)
void gemm_qkv(const ushort* __restrict__ A,
              const ushort* __restrict__ W0, const ushort* __restrict__ W1,
              const ushort* __restrict__ W2,
              ushort* __restrict__ O0, ushort* __restrict__ O1,
              ushort* __restrict__ O2)
{
    const int z = blockIdx.z;
    const ushort* W = (z == 0) ? W0 : (z == 1) ? W1 : W2;

    __shared__ alignas(16) ushort As[128][40];
    __shared__ alignas(16) ushort Bs[128][40];

    const int t = threadIdx.x;
    const int lane = t & 63, w = t >> 6;
    const int quad = lane >> 4, l15 = lane & 15;
    const int wm = (w >> 1) * 64, wn = (w & 1) * 64;
    const int tileM = blockIdx.x * 128, tileN = blockIdx.y * 128;

    const int r0 = t >> 2, r1 = 64 + (t >> 2);
    const int cg = (t & 3) * 8;
    const ushort* GA0 = A + (size_t)(tileM + r0) * D_ + cg;
    const ushort* GA1 = A + (size_t)(tileM + r1) * D_ + cg;
    const ushort* GB0 = W + (size_t)(tileN + r0) * D_ + cg;
    const ushort* GB1 = W + (size_t)(tileN + r1) * D_ + cg;

    f32x4 acc[4][4];
#pragma unroll
    for (int mt = 0; mt < 4; ++mt)
#pragma unroll
        for (int nt = 0; nt < 4; ++nt) acc[mt][nt] = (f32x4){0.f, 0.f, 0.f, 0.f};

    uint4 pa0 = *(const uint4*)GA0, pa1 = *(const uint4*)GA1;
    uint4 pb0 = *(const uint4*)GB0, pb1 = *(const uint4*)GB1;

    for (int k0 = 0; k0 < D_; k0 += 32) {
        __syncthreads();                 // prev tile's readers done
        *(uint4*)&As[r0][cg] = pa0;
        *(uint4*)&As[r1][cg] = pa1;
        *(uint4*)&Bs[r0][cg] = pb0;
        *(uint4*)&Bs[r1][cg] = pb1;
        __syncthreads();
        if (k0 + 32 < D_) {              // prefetch next tile (used next iter)
            pa0 = *(const uint4*)(GA0 + k0 + 32);
            pa1 = *(const uint4*)(GA1 + k0 + 32);
            pb0 = *(const uint4*)(GB0 + k0 + 32);
            pb1 = *(const uint4*)(GB1 + k0 + 32);
        }

        bf16x8 af[4], bf[4];
#pragma unroll
        for (int mt = 0; mt < 4; ++mt) af[mt] = *(const bf16x8*)&As[wm + mt * 16 + l15][quad * 8];
#pragma unroll
        for (int nt = 0; nt < 4; ++nt) bf[nt] = *(const bf16x8*)&Bs[wn + nt * 16 + l15][quad * 8];
#pragma unroll
        for (int mt = 0; mt < 4; ++mt)
#pragma unroll
            for (int nt = 0; nt < 4; ++nt)
                acc[mt][nt] = __builtin_amdgcn_mfma_f32_16x16x32_bf16(af[mt], bf[nt], acc[mt][nt], 0, 0, 0);
    }

    ushort* O = (z == 0) ? O0 : (z == 1) ? O1 : O2;
    // Q: fold 1/sqrt(64) AND log2e (exp2-domain softmax) into the scale
    const float scl = (z == 0) ? 0.18033688f : 1.0f;
#pragma unroll
    for (int mt = 0; mt < 4; ++mt)
#pragma unroll
        for (int nt = 0; nt < 4; ++nt) {
            if (z == 2) {
                // V transposed: Vt[bh][dd][n], 4 consecutive n per 8B store
                int rg0 = tileM + wm + mt * 16 + quad * 4;
                int cgc = tileN + wn + nt * 16 + l15;
                int b = rg0 >> 11, n0 = rg0 & (N_ - 1);
                int h = cgc >> 6, dd = cgc & 63;
                ushort4 o4;
                o4.x = f2b(acc[mt][nt][0]); o4.y = f2b(acc[mt][nt][1]);
                o4.z = f2b(acc[mt][nt][2]); o4.w = f2b(acc[mt][nt][3]);
                *(ushort4*)&O[((size_t)((b * H_ + h) * HD_ + dd)) * N_ + n0] = o4;
            } else {
#pragma unroll
                for (int r = 0; r < 4; ++r) {
                    int rg = tileM + wm + mt * 16 + quad * 4 + r;
                    int cgc = tileN + wn + nt * 16 + l15;
                    int b = rg >> 11, n = rg & (N_ - 1);
                    int h = cgc >> 6, dd = cgc & 63;
                    O[(((size_t)(b * H_ + h)) * N_ + n) * HD_ + dd] = f2b(acc[mt][nt][r] * scl);
                }
            }
        }
}

// ---------------------------------------------------------------------------
// Final GEMM: out = AO @ Wo^T + bias, fp32 out [4096x1024].
// 128x64 tile (512 blocks = 2/CU). 4 waves 2x2, each 64x32.
// Register-prefetch staging.
// ---------------------------------------------------------------------------
__global__ __launch_bounds__(256)
void gemm_fin(const ushort* __restrict__ A, const ushort* __restrict__ W,
              const float* __restrict__ bias, float* __restrict__ Of)
{
    __shared__ alignas(16) ushort As[128][40];
    __shared__ alignas(16) ushort Bs[64][40];

    const int t = threadIdx.x;
    const int lane = t & 63, w = t >> 6;
    const int quad = lane >> 4, l15 = lane & 15;
    const int wm = (w >> 1) * 64, wn = (w & 1) * 32;
    const int tileM = blockIdx.x * 128, tileN = blockIdx.y * 64;

    const int r0 = t >> 2, r1 = 64 + (t >> 2);
    const int cg = (t & 3) * 8;
    const ushort* GA0 = A + (size_t)(tileM + r0) * D_ + cg;
    const ushort* GA1 = A + (size_t)(tileM + r1) * D_ + cg;
    const ushort* GB0 = W + (size_t)(tileN + r0) * D_ + cg;

    f32x4 acc[4][2];
#pragma unroll
    for (int mt = 0; mt < 4; ++mt)
#pragma unroll
        for (int nt = 0; nt < 2; ++nt) acc[mt][nt] = (f32x4){0.f, 0.f, 0.f, 0.f};

    uint4 pa0 = *(const uint4*)GA0, pa1 = *(const uint4*)GA1;
    uint4 pb0 = *(const uint4*)GB0;

    for (int k0 = 0; k0 < D_; k0 += 32) {
        __syncthreads();
        *(uint4*)&As[r0][cg] = pa0;
        *(uint4*)&As[r1][cg] = pa1;
        *(uint4*)&Bs[r0 & 63][cg] = pb0;
        __syncthreads();
        if (k0 + 32 < D_) {
            pa0 = *(const uint4*)(GA0 + k0 + 32);
            pa1 = *(const uint4*)(GA1 + k0 + 32);
            pb0 = *(const uint4*)(GB0 + k0 + 32);
        }

        bf16x8 af[4], bf[2];
#pragma unroll
        for (int mt = 0; mt < 4; ++mt) af[mt] = *(const bf16x8*)&As[wm + mt * 16 + l15][quad * 8];
#pragma unroll
        for (int nt = 0; nt < 2; ++nt) bf[nt] = *(const bf16x8*)&Bs[wn + nt * 16 + l15][quad * 8];
#pragma unroll
        for (int mt = 0; mt < 4; ++mt)
#pragma unroll
            for (int nt = 0; nt < 2; ++nt)
                acc[mt][nt] = __builtin_amdgcn_mfma_f32_16x16x32_bf16(af[mt], bf[nt], acc[mt][nt], 0, 0, 0);
    }

#pragma unroll
    for (int mt = 0; mt < 4; ++mt)
#pragma unroll
        for (int nt = 0; nt < 2; ++nt)
#pragma unroll
            for (int r = 0; r < 4; ++r) {
                int rg = tileM + wm + mt * 16 + quad * 4 + r;
                int cgc = tileN + wn + nt * 16 + l15;
                Of[(size_t)rg * D_ + cgc] = acc[mt][nt][r] + bias[cgc];
            }
}

// ---------------------------------------------------------------------------
// MFMA adaptive-temperature causal flash attention (LDS-staged, reg-prefetch,
// PAIRED-UNIFORM work items, exp2-domain).
// R7 insight: grid 1024 = 4 blocks/CU were ALL co-resident, so LPT ordering
// did nothing; per-CU drain (short-qt blocks finishing early) was the
// imbalance. Fix: 512 blocks, each runs TWO complementary items
// (qt=31-p, then qt=p) -> exactly 33 kb-iterations per pass per block.
// Perfectly uniform by construction; zero tail.
// bh = bid&31 -> XCD ~ bh%8 K/V L2 locality preserved.
// exp2 domain: Q pre-scaled by 0.125*log2e, so scores s2 = s*log2e.
//   Z  = sum 2^(s2-C2), S2 = sum (s2-C2)*2^(s2-C2), C2 = 8*log2e
//   H  = ln2*(log2(Z) - S2/Z)   (natural-domain entropy)
//   w  = 2^(beta*(s2-C2)) = exp2(fma(beta, s2, -beta*C2))
// v_exp_f32/v_log_f32 are natively base-2: saves the ln2-mul per exp.
// Pass 2: O += w*V via MFMA (P through wave-private LDS), Z' += w; O/Z'.
// ---------------------------------------------------------------------------
__global__ __launch_bounds__(256)
void attn_mfma(const ushort* __restrict__ Q, const ushort* __restrict__ K,
               const ushort* __restrict__ VT, ushort* __restrict__ AO)
{
    const int bid = blockIdx.x;
    const int p  = bid >> 5;           // 0..15
    const int bh = bid & 31;
    const size_t kvbase = (size_t)bh * N_ * HD_;

    __shared__ alignas(16) ushort Ks[64][72];       // [key][hd]
    __shared__ alignas(16) ushort Vt[64][72];       // [hd][key]
    __shared__ alignas(16) ushort Ps[4][4][296];    // wave-private P, grp-padded

    const int t = threadIdx.x;
    const int lane = t & 63, w = t >> 6;
    const int quad = lane >> 4, l15 = lane & 15;
    const float SH2 = 11.5416913f;     // 8 * log2(e)
    const float LN2 = 0.69314718f;

    const int skey = t >> 3;            // 0..31
    const int skc  = (t & 7) * 8;       // 0..56
    const ushort* KS0 = K  + kvbase + (size_t)skey * HD_ + skc;        // + kb*64*HD_
    const ushort* KS1 = KS0 + 32 * HD_;
    const ushort* VS0 = VT + kvbase + (size_t)skey * N_ + skc;         // + kb*64
    const ushort* VS1 = VS0 + 32 * N_;

    const int qrow = w * 16 + quad * 4;
    const int b = bh >> 4, h = bh & 15;

    for (int item = 0; item < 2; ++item) {
        const int qt = item ? p : (31 - p);    // complementary pair: uniform work

        // Q fragments for this item
        bf16x8 aq0, aq1;
        {
            const size_t qr = kvbase + (size_t)(qt * 64 + w * 16 + l15) * HD_;
            aq0 = *(const bf16x8*)&Q[qr + quad * 8];
            aq1 = *(const bf16x8*)&Q[qr + 32 + quad * 8];
        }

        float ez[4] = {0.f, 0.f, 0.f, 0.f};
        float sz[4] = {0.f, 0.f, 0.f, 0.f};

        // ---------------- pass 1: Z, S2 ----------------
        uint4 pk0 = *(const uint4*)KS0;
        uint4 pk1 = *(const uint4*)KS1;
        for (int kb = 0; kb <= qt; ++kb) {
            __syncthreads();                       // prev tile's readers done
            *(uint4*)&Ks[skey][skc]      = pk0;    // vmcnt wait hidden by prev compute
            *(uint4*)&Ks[32 + skey][skc] = pk1;
            __syncthreads();
            if (kb < qt) {                         // prefetch kb+1
                pk0 = *(const uint4*)(KS0 + (size_t)(kb + 1) * (64 * HD_));
                pk1 = *(const uint4*)(KS1 + (size_t)(kb + 1) * (64 * HD_));
            }
            if (kb < qt) {                         // off-diagonal: no masks
#pragma unroll
                for (int nt = 0; nt < 4; ++nt) {
                    f32x4 sv = (f32x4){0.f, 0.f, 0.f, 0.f};
                    sv = __builtin_amdgcn_mfma_f32_16x16x32_bf16(aq0, *(const bf16x8*)&Ks[nt * 16 + l15][quad * 8], sv, 0, 0, 0);
                    sv = __builtin_amdgcn_mfma_f32_16x16x32_bf16(aq1, *(const bf16x8*)&Ks[nt * 16 + l15][32 + quad * 8], sv, 0, 0, 0);
#pragma unroll
                    for (int r = 0; r < 4; ++r) {
                        float sh = sv[r] - SH2;
                        float e = __builtin_amdgcn_exp2f(sh);
                        ez[r] += e;
                        sz[r] = fmaf(e, sh, sz[r]);
                    }
                }
            } else {                               // diagonal: causal mask
#pragma unroll
                for (int nt = 0; nt < 4; ++nt) {
                    f32x4 sv = (f32x4){0.f, 0.f, 0.f, 0.f};
                    sv = __builtin_amdgcn_mfma_f32_16x16x32_bf16(aq0, *(const bf16x8*)&Ks[nt * 16 + l15][quad * 8], sv, 0, 0, 0);
                    sv = __builtin_amdgcn_mfma_f32_16x16x32_bf16(aq1, *(const bf16x8*)&Ks[nt * 16 + l15][32 + quad * 8], sv, 0, 0, 0);
                    const int kcol = nt * 16 + l15;
#pragma unroll
                    for (int r = 0; r < 4; ++r) {
                        float sh = sv[r] - SH2;
                        float e = (kcol <= qrow + r) ? __builtin_amdgcn_exp2f(sh) : 0.f;
                        ez[r] += e;
                        sz[r] = fmaf(e, sh, sz[r]);
                    }
                }
            }
        }
        // hoisted 16-lane butterfly reduce
#pragma unroll
        for (int r = 0; r < 4; ++r) {
#pragma unroll
            for (int off = 1; off < 16; off <<= 1) {
                ez[r] += __shfl_xor(ez[r], off);
                sz[r] += __shfl_xor(sz[r], off);
            }
        }

        // ---------------- entropy -> beta ----------------
        float nbs[4], bl[4];   // w = exp2(fma(beta, s2, -beta*SH2))
#pragma unroll
        for (int r = 0; r < 4; ++r) {
            float Z = ez[r];
            float Hh = LN2 * (__builtin_amdgcn_logf(Z) - sz[r] / Z);
            float bb = 1.f;
            if (Hh > 0.5f) {
                float e2 = Hh * Hh;
                float pp = -0.037f * e2 * e2 + 0.481f * e2 * Hh - 2.3f * e2 + 4.917f * Hh - 1.791f;
                bb = fmaxf(pp, 1.f);
            }
            bl[r] = bb;
            nbs[r] = -bb * SH2;
        }

        // ---------------- pass 2: O, Z' ----------------
        f32x4 ov[4];
#pragma unroll
        for (int nt = 0; nt < 4; ++nt) ov[nt] = (f32x4){0.f, 0.f, 0.f, 0.f};
        float zp[4] = {0.f, 0.f, 0.f, 0.f};

        pk0 = *(const uint4*)KS0;
        pk1 = *(const uint4*)KS1;
        uint4 pv0 = *(const uint4*)VS0;
        uint4 pv1 = *(const uint4*)VS1;
        for (int kb = 0; kb <= qt; ++kb) {
            __syncthreads();
            *(uint4*)&Ks[skey][skc]      = pk0;
            *(uint4*)&Ks[32 + skey][skc] = pk1;
            *(uint4*)&Vt[skey][skc]      = pv0;
            *(uint4*)&Vt[32 + skey][skc] = pv1;
            __syncthreads();
            if (kb < qt) {
                pk0 = *(const uint4*)(KS0 + (size_t)(kb + 1) * (64 * HD_));
                pk1 = *(const uint4*)(KS1 + (size_t)(kb + 1) * (64 * HD_));
                pv0 = *(const uint4*)(VS0 + (kb + 1) * 64);
                pv1 = *(const uint4*)(VS1 + (kb + 1) * 64);
            }
            const bool diag = (kb == qt);

            float wv[4][4];
#pragma unroll
            for (int nt = 0; nt < 4; ++nt) {
                f32x4 sv = (f32x4){0.f, 0.f, 0.f, 0.f};
                sv = __builtin_amdgcn_mfma_f32_16x16x32_bf16(aq0, *(const bf16x8*)&Ks[nt * 16 + l15][quad * 8], sv, 0, 0, 0);
                sv = __builtin_amdgcn_mfma_f32_16x16x32_bf16(aq1, *(const bf16x8*)&Ks[nt * 16 + l15][32 + quad * 8], sv, 0, 0, 0);
                const int kcol = nt * 16 + l15;
#pragma unroll
                for (int r = 0; r < 4; ++r) {
                    float e = __builtin_amdgcn_exp2f(fmaf(bl[r], sv[r], nbs[r]));
                    wv[nt][r] = (!diag || (kcol <= qrow + r)) ? e : 0.f;
                }
            }
            // P -> wave-private LDS (C-layout write, A-layout read; same-wave)
#pragma unroll
            for (int nt = 0; nt < 4; ++nt)
#pragma unroll
                for (int r = 0; r < 4; ++r)
                    Ps[w][quad][r * 72 + nt * 16 + l15] = f2b_fast(wv[nt][r]);
#pragma unroll
            for (int r = 0; r < 4; ++r)
                zp[r] += (wv[0][r] + wv[1][r]) + (wv[2][r] + wv[3][r]);

            bf16x8 pa0 = *(const bf16x8*)&Ps[w][l15 >> 2][(l15 & 3) * 72 + quad * 8];
            bf16x8 pa1 = *(const bf16x8*)&Ps[w][l15 >> 2][(l15 & 3) * 72 + 32 + quad * 8];
#pragma unroll
            for (int nt = 0; nt < 4; ++nt) {
                ov[nt] = __builtin_amdgcn_mfma_f32_16x16x32_bf16(pa0, *(const bf16x8*)&Vt[nt * 16 + l15][quad * 8], ov[nt], 0, 0, 0);
                ov[nt] = __builtin_amdgcn_mfma_f32_16x16x32_bf16(pa1, *(const bf16x8*)&Vt[nt * 16 + l15][32 + quad * 8], ov[nt], 0, 0, 0);
            }
        }
        // hoisted Z' butterfly
#pragma unroll
        for (int r = 0; r < 4; ++r)
#pragma unroll
            for (int off = 1; off < 16; off <<= 1) zp[r] += __shfl_xor(zp[r], off);

        // ---------------- write AO [B, N, D] bf16 ----------------
#pragma unroll
        for (int r = 0; r < 4; ++r) {
            int qg = qt * 64 + w * 16 + quad * 4 + r;
            float inv = 1.f / zp[r];
            size_t rowoff = ((size_t)(b * N_ + qg)) * D_ + h * HD_;
#pragma unroll
            for (int nt = 0; nt < 4; ++nt)
                AO[rowoff + nt * 16 + l15] = f2b(ov[nt][r] * inv);
        }
    }
}

// ---------------------------------------------------------------------------
extern "C" void kernel_launch(void* const* d_in, const int* in_sizes, int n_in,
                              void* d_out, int out_size, void* d_ws, size_t ws_size,
                              hipStream_t stream)
{
    const float* x  = (const float*)d_in[0];
    const float* Wq = (const float*)d_in[1];
    const float* Wk = (const float*)d_in[2];
    const float* Wv = (const float*)d_in[3];
    const float* Wo = (const float*)d_in[4];
    const float* bo = (const float*)d_in[5];
    float* out = (float*)d_out;

    ushort* ws  = (ushort*)d_ws;
    ushort* xb  = ws;                       // 4096*1024
    ushort* wqb = ws + 4194304;
    ushort* wkb = ws + 5242880;
    ushort* wvb = ws + 6291456;
    ushort* wob = ws + 7340032;
    ushort* Qb  = ws + 8388608;             // [32][2048][64]
    ushort* Kb  = ws + 12582912;            // [32][2048][64]
    ushort* Vtb = ws + 16777216;            // [32][64][2048]  (transposed V)
    ushort* aob = ws + 20971520;            // 4096*1024

    cvt_all<<<8192, 256, 0, stream>>>(x, Wq, Wk, Wv, Wo, xb);

    gemm_qkv<<<dim3(32, 8, 3), 256, 0, stream>>>(
        xb, wqb, wkb, wvb, Qb, Kb, Vtb);

    attn_mfma<<<dim3(512), 256, 0, stream>>>(Qb, Kb, Vtb, aob);

    gemm_fin<<<dim3(32, 16), 256, 0, stream>>>(aob, wob, bo, out);
}